// Round 1
// baseline (263.029 us; speedup 1.0000x reference)
//
#include <hip/hip_runtime.h>
#include <math.h>

#define FH 384
#define FW 384
#define DH 96
#define DW 96
#define NIMG 6   // 0,1: pred b0,b1; 2,3: I[:,0] b0,b1; 4,5: I[:,1] b0,b1

// Keys cubic kernel, a = -0.5 (matches jax.image "cubic")
__device__ __forceinline__ float keysc(float x) {
    if (x < 1.f) return ((1.5f * x - 2.5f) * x) * x + 1.f;
    if (x < 2.f) return ((-0.5f * x + 2.5f) * x - 4.f) * x + 2.f;
    return 0.f;
}

// reflect-101 (jnp.pad mode='reflect'), valid for i in [-(n-1), 2n-2]
__device__ __forceinline__ int refl(int i, int n) {
    if (i < 0) i = -i;
    if (i >= n) i = 2 * (n - 1) - i;
    return i;
}

// ---------------- K1: grayscale for 6 images -------------------------------
__global__ void k_gray(const float* __restrict__ pred, const float* __restrict__ I,
                       float* __restrict__ gray) {
    int idx = blockIdx.x * 256 + threadIdx.x;
    const int total = NIMG * FH * FW;
    if (idx >= total) return;
    int img = idx / (FH * FW);
    int px  = idx % (FH * FW);
    const float* src;
    if (img < 2) {
        src = pred + img * 3 * FH * FW;
    } else {
        int j = (img - 2) >> 1, b = (img - 2) & 1;
        src = I + ((b * 2 + j) * 3) * FH * FW;
    }
    float r = src[px], g = src[FH * FW + px], b = src[2 * FH * FW + px];
    gray[idx] = (0.299f * r + 0.587f * g + 0.114f * b) * 255.0f;
}

// ---------------- K2: census + downsample along H --------------------------
// out CH[img][k][yo][x], k in 0..8 (census channel), x full-res col
__global__ void k_census_downH(const float* __restrict__ gray, float* __restrict__ CH) {
    int idx = blockIdx.x * 256 + threadIdx.x;
    const int total = NIMG * 9 * DH * FW;
    if (idx >= total) return;
    int x  = idx % FW;
    int t1 = idx / FW;
    int yo = t1 % DH;
    int t2 = t1 / DH;
    int k  = t2 % 9;
    int img = t2 / 9;
    int dy = k / 3 - 1, dx = k % 3 - 1;
    const float* g = gray + img * FH * FW;
    float acc = 0.f, z = 0.f;
#pragma unroll
    for (int t = 0; t < 16; ++t) {
        int r = 4 * yo - 6 + t;
        if (r < 0 || r >= FH) continue;
        float w = keysc(fabsf((float)t - 7.5f) * 0.25f);
        z += w;
        float gc = g[r * FW + x];
        int r2 = r + dy, c2 = x + dx;
        float gn = (r2 < 0 || r2 >= FH || c2 < 0 || c2 >= FW) ? 0.f : g[r2 * FW + c2];
        float tt = gn - gc;
        acc += w * (tt / sqrtf(0.81f + tt * tt));
    }
    CH[idx] = acc / z;
}

// ---------------- K3: generic downsample along W ---------------------------
// src: [nrows][FW] -> dst: [nrows][DW]
__global__ void k_downW(const float* __restrict__ src, float* __restrict__ dst, int nrows) {
    int idx = blockIdx.x * 256 + threadIdx.x;
    int total = nrows * DW;
    if (idx >= total) return;
    int xo = idx % DW;
    int row = idx / DW;
    const float* s = src + row * FW;
    float acc = 0.f, z = 0.f;
#pragma unroll
    for (int t = 0; t < 16; ++t) {
        int i = 4 * xo - 6 + t;
        if (i < 0 || i >= FW) continue;
        float w = keysc(fabsf((float)t - 7.5f) * 0.25f);
        z += w;
        acc += w * s[i];
    }
    dst[idx] = acc / z;
}

// ---------------- K4: raw channels downsample along H ----------------------
// out RH[img][c][yo][x]
__global__ void k_raw_downH(const float* __restrict__ pred, const float* __restrict__ I,
                            float* __restrict__ RH) {
    int idx = blockIdx.x * 256 + threadIdx.x;
    const int total = NIMG * 3 * DH * FW;
    if (idx >= total) return;
    int x  = idx % FW;
    int t1 = idx / FW;
    int yo = t1 % DH;
    int t2 = t1 / DH;
    int c  = t2 % 3;
    int img = t2 / 3;
    const float* src;
    if (img < 2) {
        src = pred + (img * 3 + c) * FH * FW;
    } else {
        int j = (img - 2) >> 1, b = (img - 2) & 1;
        src = I + (((b * 2 + j) * 3) + c) * FH * FW;
    }
    float acc = 0.f, z = 0.f;
#pragma unroll
    for (int t = 0; t < 16; ++t) {
        int r = 4 * yo - 6 + t;
        if (r < 0 || r >= FH) continue;
        float w = keysc(fabsf((float)t - 7.5f) * 0.25f);
        z += w;
        acc += w * src[r * FW + x];
    }
    RH[idx] = acc / z;
}

// ---------------- K6: patch matching + loss --------------------------------
// CD: [NIMG][9][DH][DW] census downsampled; RD: [NIMG][3][DH][DW] raw downsampled
__global__ __launch_bounds__(256) void k_match(const float* __restrict__ CD,
                                               const float* __restrict__ RD,
                                               float* __restrict__ partial) {
    int bid = blockIdx.x;              // b*36 + tile
    int b   = bid / 36;
    int rem = bid % 36;
    int y = (rem / 6) * 16 + threadIdx.x / 16;
    int x = (rem % 6) * 16 + threadIdx.x % 16;

    const int PLANE = DH * DW;
    const float* CDp = CD + b * 9 * PLANE;

    int ry0[3], rx0[3];
#pragma unroll
    for (int kk = 0; kk < 3; ++kk) {
        ry0[kk] = refl(y + kk - 1, DH);
        rx0[kk] = refl(x + kk - 1, DW);
    }

    float p[81];
    float p2 = 0.f;
#pragma unroll
    for (int f = 0; f < 81; ++f) {
        int c = f / 9, ky = (f / 3) % 3, kx = f % 3;
        float v = CDp[(c * DH + ry0[ky]) * DW + rx0[kx]];
        p[f] = v;
        p2 += v * v;
    }

    float best = INFINITY;
    int bestn = 0;
    for (int n = 0; n < 98; ++n) {
        int j = n / 49, rr = n % 49;
        int dy = rr / 7 - 3, dx = rr % 7 - 3;
        int yy = refl(y + dy, DH), xx = refl(x + dx, DW);  // first reflect
        const float* CDn = CD + (2 + 2 * j + b) * 9 * PLANE;
        int ry[3], rx[3];
#pragma unroll
        for (int kk = 0; kk < 3; ++kk) {       // second reflect (patch of patch)
            ry[kk] = refl(yy + kk - 1, DH);
            rx[kk] = refl(xx + kk - 1, DW);
        }
        float n2 = 0.f, dot = 0.f;
#pragma unroll
        for (int f = 0; f < 81; ++f) {
            int c = f / 9, ky = (f / 3) % 3, kx = f % 3;
            float v = CDn[(c * DH + ry[ky]) * DW + rx[kx]];
            n2 += v * v;
            dot += p[f] * v;
        }
        float dis = p2 + n2 - 2.f * dot;       // same formula as reference
        if (dis < best) { best = dis; bestn = n; }   // first-occurrence min
    }

    // gather matched raw patch, accumulate squared diff
    int j = bestn / 49, rr = bestn % 49;
    int dy = rr / 7 - 3, dx = rr % 7 - 3;
    int yy = refl(y + dy, DH), xx = refl(x + dx, DW);
    int ry[3], rx[3];
#pragma unroll
    for (int kk = 0; kk < 3; ++kk) {
        ry[kk] = refl(yy + kk - 1, DH);
        rx[kk] = refl(xx + kk - 1, DW);
    }
    const float* RDp = RD + b * 3 * PLANE;
    const float* RDn = RD + (2 + 2 * j + b) * 3 * PLANE;
    float loss = 0.f;
#pragma unroll
    for (int f = 0; f < 27; ++f) {
        int c = f / 9, ky = (f / 3) % 3, kx = f % 3;
        float a = RDp[(c * DH + ry0[ky]) * DW + rx0[kx]];
        float m = RDn[(c * DH + ry[ky]) * DW + rx[kx]];
        float d = a - m;
        loss += d * d;
    }

    __shared__ float red[256];
    red[threadIdx.x] = loss;
    __syncthreads();
#pragma unroll
    for (int s = 128; s > 0; s >>= 1) {
        if (threadIdx.x < s) red[threadIdx.x] += red[threadIdx.x + s];
        __syncthreads();
    }
    if (threadIdx.x == 0) partial[bid] = red[0];
}

// ---------------- K7: final reduction --------------------------------------
__global__ void k_final(const float* __restrict__ partial, float* __restrict__ out) {
    __shared__ float red[128];
    float v = (threadIdx.x < 72) ? partial[threadIdx.x] : 0.f;
    red[threadIdx.x] = v;
    __syncthreads();
#pragma unroll
    for (int s = 64; s > 0; s >>= 1) {
        if (threadIdx.x < s) red[threadIdx.x] += red[threadIdx.x + s];
        __syncthreads();
    }
    // mean over [b=2, hw=9216, 27] with the 0.5 factor
    if (threadIdx.x == 0) out[0] = red[0] * (0.5f / 497664.0f);
}

extern "C" void kernel_launch(void* const* d_in, const int* in_sizes, int n_in,
                              void* d_out, int out_size, void* d_ws, size_t ws_size,
                              hipStream_t stream) {
    const float* pred = (const float*)d_in[0];   // [2,3,384,384]
    const float* I    = (const float*)d_in[1];   // [2,2,3,384,384]
    float* out = (float*)d_out;
    float* ws  = (float*)d_ws;

    // workspace layout (floats)
    float* gray = ws;                       // 6*384*384      =  884736
    float* CH   = gray + 884736;            // 6*9*96*384     = 1990656
    float* CD   = CH + 1990656;             // 6*9*96*96      =  497664
    float* RH   = CD + 497664;              // 6*3*96*384     =  663552
    float* RD   = RH + 663552;              // 6*3*96*96      =  165888
    float* part = RD + 165888;              // 72

    k_gray<<<(NIMG * FH * FW + 255) / 256, 256, 0, stream>>>(pred, I, gray);
    k_census_downH<<<(NIMG * 9 * DH * FW + 255) / 256, 256, 0, stream>>>(gray, CH);
    k_downW<<<(NIMG * 9 * DH * DW + 255) / 256, 256, 0, stream>>>(CH, CD, NIMG * 9 * DH);
    k_raw_downH<<<(NIMG * 3 * DH * FW + 255) / 256, 256, 0, stream>>>(pred, I, RH);
    k_downW<<<(NIMG * 3 * DH * DW + 255) / 256, 256, 0, stream>>>(RH, RD, NIMG * 3 * DH);
    k_match<<<72, 256, 0, stream>>>(CD, RD, part);
    k_final<<<1, 128, 0, stream>>>(part, out);
}

// Round 2
// 205.298 us; speedup vs baseline: 1.2812x; 1.2812x over previous
//
#include <hip/hip_runtime.h>
#include <math.h>

#define FH 384
#define FW 384
#define DH 96
#define DW 96
#define NIMG 6   // 0,1: pred b0,b1; 2,3: I[:,0] b0,b1; 4,5: I[:,1] b0,b1

// Keys cubic kernel, a = -0.5 (matches jax.image "cubic")
__device__ __forceinline__ float keysc(float x) {
    if (x < 1.f) return ((1.5f * x - 2.5f) * x) * x + 1.f;
    if (x < 2.f) return ((-0.5f * x + 2.5f) * x - 4.f) * x + 2.f;
    return 0.f;
}

// reflect-101 (jnp.pad mode='reflect'), valid for i in [-(n-1), 2n-2]
__device__ __forceinline__ int refl(int i, int n) {
    if (i < 0) i = -i;
    if (i >= n) i = 2 * (n - 1) - i;
    return i;
}

// ---------------- K1: grayscale for 6 images -------------------------------
__global__ void k_gray(const float* __restrict__ pred, const float* __restrict__ I,
                       float* __restrict__ gray) {
    int idx = blockIdx.x * 256 + threadIdx.x;
    const int total = NIMG * FH * FW;
    if (idx >= total) return;
    int img = idx / (FH * FW);
    int px  = idx % (FH * FW);
    const float* src;
    if (img < 2) {
        src = pred + img * 3 * FH * FW;
    } else {
        int j = (img - 2) >> 1, b = (img - 2) & 1;
        src = I + ((b * 2 + j) * 3) * FH * FW;
    }
    float r = src[px], g = src[FH * FW + px], b = src[2 * FH * FW + px];
    gray[idx] = (0.299f * r + 0.587f * g + 0.114f * b) * 255.0f;
}

// ---------------- K2: census + downsample along H --------------------------
// out CH[img][k][yo][x], k in 0..8 (census channel), x full-res col
__global__ void k_census_downH(const float* __restrict__ gray, float* __restrict__ CH) {
    int idx = blockIdx.x * 256 + threadIdx.x;
    const int total = NIMG * 9 * DH * FW;
    if (idx >= total) return;
    int x  = idx % FW;
    int t1 = idx / FW;
    int yo = t1 % DH;
    int t2 = t1 / DH;
    int k  = t2 % 9;
    int img = t2 / 9;
    int dy = k / 3 - 1, dx = k % 3 - 1;
    const float* g = gray + img * FH * FW;
    float acc = 0.f, z = 0.f;
#pragma unroll
    for (int t = 0; t < 16; ++t) {
        int r = 4 * yo - 6 + t;
        if (r < 0 || r >= FH) continue;
        float w = keysc(fabsf((float)t - 7.5f) * 0.25f);
        z += w;
        float gc = g[r * FW + x];
        int r2 = r + dy, c2 = x + dx;
        float gn = (r2 < 0 || r2 >= FH || c2 < 0 || c2 >= FW) ? 0.f : g[r2 * FW + c2];
        float tt = gn - gc;
        acc += w * (tt / sqrtf(0.81f + tt * tt));
    }
    CH[idx] = acc / z;
}

// ---------------- K3: generic downsample along W ---------------------------
// src: [nrows][FW] -> dst: [nrows][DW]  (CH|RH -> CD|RD, laid out contiguously)
__global__ void k_downW(const float* __restrict__ src, float* __restrict__ dst, int nrows) {
    int idx = blockIdx.x * 256 + threadIdx.x;
    int total = nrows * DW;
    if (idx >= total) return;
    int xo = idx % DW;
    int row = idx / DW;
    const float* s = src + row * FW;
    float acc = 0.f, z = 0.f;
#pragma unroll
    for (int t = 0; t < 16; ++t) {
        int i = 4 * xo - 6 + t;
        if (i < 0 || i >= FW) continue;
        float w = keysc(fabsf((float)t - 7.5f) * 0.25f);
        z += w;
        acc += w * s[i];
    }
    dst[idx] = acc / z;
}

// ---------------- K4: raw channels downsample along H ----------------------
// out RH[img][c][yo][x]
__global__ void k_raw_downH(const float* __restrict__ pred, const float* __restrict__ I,
                            float* __restrict__ RH) {
    int idx = blockIdx.x * 256 + threadIdx.x;
    const int total = NIMG * 3 * DH * FW;
    if (idx >= total) return;
    int x  = idx % FW;
    int t1 = idx / FW;
    int yo = t1 % DH;
    int t2 = t1 / DH;
    int c  = t2 % 3;
    int img = t2 / 3;
    const float* src;
    if (img < 2) {
        src = pred + (img * 3 + c) * FH * FW;
    } else {
        int j = (img - 2) >> 1, b = (img - 2) & 1;
        src = I + (((b * 2 + j) * 3) + c) * FH * FW;
    }
    float acc = 0.f, z = 0.f;
#pragma unroll
    for (int t = 0; t < 16; ++t) {
        int r = 4 * yo - 6 + t;
        if (r < 0 || r >= FH) continue;
        float w = keysc(fabsf((float)t - 7.5f) * 0.25f);
        z += w;
        acc += w * src[r * FW + x];
    }
    RH[idx] = acc / z;
}

// ---------------- K6: patch matching + loss, one wave per pixel ------------
// CD: [NIMG][9][DH][DW]; RD: [NIMG][3][DH][DW]
__global__ __launch_bounds__(256) void k_match(const float* __restrict__ CD,
                                               const float* __restrict__ RD,
                                               float* __restrict__ partial) {
    const int PLANE = DH * DW;
    int wid  = threadIdx.x >> 6;
    int lane = threadIdx.x & 63;
    int pid  = blockIdx.x * 4 + wid;       // 0..18431
    int b = pid / PLANE;
    int p = pid % PLANE;
    int y = p / DW, x = p % DW;

    const float* CDp = CD + b * 9 * PLANE;

    int ry0[3], rx0[3];
#pragma unroll
    for (int kk = 0; kk < 3; ++kk) {
        ry0[kk] = refl(y + kk - 1, DH);
        rx0[kk] = refl(x + kk - 1, DW);
    }

    // stage center census patch (81 floats) into per-wave LDS
    __shared__ float pl[4][88];
    for (int f = lane; f < 81; f += 64) {
        int c = f / 9, ky = (f / 3) % 3, kx = f % 3;
        pl[wid][f] = CDp[(c * DH + ry0[ky]) * DW + rx0[kx]];
    }
    __syncthreads();

    // each lane evaluates candidates n = lane and n = lane + 64
    float best = INFINITY;
    int bestn = 127;
#pragma unroll
    for (int t = 0; t < 2; ++t) {
        int n = lane + 64 * t;
        if (n < 98) {
            int j = n / 49, rr = n % 49;
            int dy = rr / 7 - 3, dx = rr % 7 - 3;
            int yy = refl(y + dy, DH), xx = refl(x + dx, DW);   // first reflect
            const float* CDn = CD + (2 + 2 * j + b) * 9 * PLANE;
            int ry[3], rx[3];
#pragma unroll
            for (int kk = 0; kk < 3; ++kk) {                    // second reflect
                ry[kk] = refl(yy + kk - 1, DH);
                rx[kk] = refl(xx + kk - 1, DW);
            }
            float n2 = 0.f, dot = 0.f;
#pragma unroll
            for (int f = 0; f < 81; ++f) {
                int c = f / 9, ky = (f / 3) % 3, kx = f % 3;
                float q = CDn[(c * DH + ry[ky]) * DW + rx[kx]];
                n2  += q * q;
                dot += pl[wid][f] * q;
            }
            float dis = n2 - 2.f * dot;   // p2 dropped: constant per pixel, argmin unchanged
            if (dis < best || (dis == best && n < bestn)) { best = dis; bestn = n; }
        }
    }

    // wave-wide argmin with first-occurrence (smallest n) tie-break
#pragma unroll
    for (int off = 32; off > 0; off >>= 1) {
        float ob = __shfl_xor(best, off);
        int   on = __shfl_xor(bestn, off);
        if (ob < best || (ob == best && on < bestn)) { best = ob; bestn = on; }
    }

    // gather matched raw patch: lanes 0..26, one feature each
    float loss = 0.f;
    {
        int j = bestn / 49, rr = bestn % 49;
        int dy = rr / 7 - 3, dx = rr % 7 - 3;
        int yy = refl(y + dy, DH), xx = refl(x + dx, DW);
        if (lane < 27) {
            int c = lane / 9, ky = (lane / 3) % 3, kx = lane % 3;
            int ry = refl(yy + ky - 1, DH), rx = refl(xx + kx - 1, DW);
            const float* RDp = RD + b * 3 * PLANE;
            const float* RDn = RD + (2 + 2 * j + b) * 3 * PLANE;
            float a = RDp[(c * DH + ry0[ky]) * DW + rx0[kx]];
            float m = RDn[(c * DH + ry) * DW + rx];
            float d = a - m;
            loss = d * d;
        }
    }
#pragma unroll
    for (int off = 32; off > 0; off >>= 1) loss += __shfl_xor(loss, off);

    __shared__ float red[4];
    if (lane == 0) red[wid] = loss;
    __syncthreads();
    if (threadIdx.x == 0)
        partial[blockIdx.x] = red[0] + red[1] + red[2] + red[3];
}

// ---------------- K7: final reduction --------------------------------------
#define NPART 4608
__global__ void k_final(const float* __restrict__ partial, float* __restrict__ out) {
    __shared__ float red[256];
    float v = 0.f;
    for (int i = threadIdx.x; i < NPART; i += 256) v += partial[i];
    red[threadIdx.x] = v;
    __syncthreads();
#pragma unroll
    for (int s = 128; s > 0; s >>= 1) {
        if (threadIdx.x < s) red[threadIdx.x] += red[threadIdx.x + s];
        __syncthreads();
    }
    // mean over [b=2, hw=9216, 27] with the 0.5 factor
    if (threadIdx.x == 0) out[0] = red[0] * (0.5f / 497664.0f);
}

extern "C" void kernel_launch(void* const* d_in, const int* in_sizes, int n_in,
                              void* d_out, int out_size, void* d_ws, size_t ws_size,
                              hipStream_t stream) {
    const float* pred = (const float*)d_in[0];   // [2,3,384,384]
    const float* I    = (const float*)d_in[1];   // [2,2,3,384,384]
    float* out = (float*)d_out;
    float* ws  = (float*)d_ws;

    // workspace layout (floats) — CH|RH contiguous, CD|RD contiguous
    float* gray = ws;                         // 6*384*384      =  884736
    float* CH   = gray + 884736;              // 6*9*96*384     = 1990656
    float* RH   = CH + 1990656;               // 6*3*96*384     =  663552
    float* CD   = RH + 663552;                // 6*9*96*96      =  497664
    float* RD   = CD + 497664;                // 6*3*96*96      =  165888
    float* part = RD + 165888;                // 4608

    k_gray<<<(NIMG * FH * FW + 255) / 256, 256, 0, stream>>>(pred, I, gray);
    k_census_downH<<<(NIMG * 9 * DH * FW + 255) / 256, 256, 0, stream>>>(gray, CH);
    k_raw_downH<<<(NIMG * 3 * DH * FW + 255) / 256, 256, 0, stream>>>(pred, I, RH);
    // one combined W-downsample over CH|RH rows -> CD|RD
    k_downW<<<((NIMG * 12 * DH) * DW + 255) / 256, 256, 0, stream>>>(CH, CD, NIMG * 12 * DH);
    k_match<<<NPART, 256, 0, stream>>>(CD, RD, part);
    k_final<<<1, 256, 0, stream>>>(part, out);
}

// Round 3
// 143.522 us; speedup vs baseline: 1.8327x; 1.4304x over previous
//
#include <hip/hip_runtime.h>
#include <math.h>

#define FH 384
#define FW 384
#define DH 96
#define DW 96
#define NIMG 6   // 0,1: pred b0,b1; 2,3: I[:,0] b0,b1; 4,5: I[:,1] b0,b1
#define PLANE (DH * DW)

// Keys cubic kernel, a = -0.5 (matches jax.image "cubic")
__device__ __forceinline__ float keysc(float x) {
    if (x < 1.f) return ((1.5f * x - 2.5f) * x) * x + 1.f;
    if (x < 2.f) return ((-0.5f * x + 2.5f) * x - 4.f) * x + 2.f;
    return 0.f;
}

// reflect-101 (jnp.pad mode='reflect'), valid for i in [-(n-1), 2n-2]
__device__ __forceinline__ int refl(int i, int n) {
    if (i < 0) i = -i;
    if (i >= n) i = 2 * (n - 1) - i;
    return i;
}

// ---------------- K1: grayscale for 6 images -------------------------------
__global__ void k_gray(const float* __restrict__ pred, const float* __restrict__ I,
                       float* __restrict__ gray) {
    int idx = blockIdx.x * 256 + threadIdx.x;
    const int total = NIMG * FH * FW;
    if (idx >= total) return;
    int img = idx / (FH * FW);
    int px  = idx % (FH * FW);
    const float* src;
    if (img < 2) {
        src = pred + img * 3 * FH * FW;
    } else {
        int j = (img - 2) >> 1, b = (img - 2) & 1;
        src = I + ((b * 2 + j) * 3) * FH * FW;
    }
    float r = src[px], g = src[FH * FW + px], b = src[2 * FH * FW + px];
    gray[idx] = (0.299f * r + 0.587f * g + 0.114f * b) * 255.0f;
}

// ---------------- K2: census + downsample along H --------------------------
// out CH[img][k][yo][x], k in 0..8 (census channel), x full-res col
__global__ void k_census_downH(const float* __restrict__ gray, float* __restrict__ CH) {
    int idx = blockIdx.x * 256 + threadIdx.x;
    const int total = NIMG * 9 * DH * FW;
    if (idx >= total) return;
    int x  = idx % FW;
    int t1 = idx / FW;
    int yo = t1 % DH;
    int t2 = t1 / DH;
    int k  = t2 % 9;
    int img = t2 / 9;
    int dy = k / 3 - 1, dx = k % 3 - 1;
    const float* g = gray + img * FH * FW;
    float acc = 0.f, z = 0.f;
#pragma unroll
    for (int t = 0; t < 16; ++t) {
        int r = 4 * yo - 6 + t;
        if (r < 0 || r >= FH) continue;
        float w = keysc(fabsf((float)t - 7.5f) * 0.25f);
        z += w;
        float gc = g[r * FW + x];
        int r2 = r + dy, c2 = x + dx;
        float gn = (r2 < 0 || r2 >= FH || c2 < 0 || c2 >= FW) ? 0.f : g[r2 * FW + c2];
        float tt = gn - gc;
        acc += w * (tt / sqrtf(0.81f + tt * tt));
    }
    CH[idx] = acc / z;
}

// ---------------- K3: generic downsample along W ---------------------------
// src: [nrows][FW] -> dst: [nrows][DW]  (CH|RH -> CD|RD, laid out contiguously)
__global__ void k_downW(const float* __restrict__ src, float* __restrict__ dst, int nrows) {
    int idx = blockIdx.x * 256 + threadIdx.x;
    int total = nrows * DW;
    if (idx >= total) return;
    int xo = idx % DW;
    int row = idx / DW;
    const float* s = src + row * FW;
    float acc = 0.f, z = 0.f;
#pragma unroll
    for (int t = 0; t < 16; ++t) {
        int i = 4 * xo - 6 + t;
        if (i < 0 || i >= FW) continue;
        float w = keysc(fabsf((float)t - 7.5f) * 0.25f);
        z += w;
        acc += w * s[i];
    }
    dst[idx] = acc / z;
}

// ---------------- K4: raw channels downsample along H ----------------------
// out RH[img][c][yo][x]
__global__ void k_raw_downH(const float* __restrict__ pred, const float* __restrict__ I,
                            float* __restrict__ RH) {
    int idx = blockIdx.x * 256 + threadIdx.x;
    const int total = NIMG * 3 * DH * FW;
    if (idx >= total) return;
    int x  = idx % FW;
    int t1 = idx / FW;
    int yo = t1 % DH;
    int t2 = t1 / DH;
    int c  = t2 % 3;
    int img = t2 / 3;
    const float* src;
    if (img < 2) {
        src = pred + (img * 3 + c) * FH * FW;
    } else {
        int j = (img - 2) >> 1, b = (img - 2) & 1;
        src = I + (((b * 2 + j) * 3) + c) * FH * FW;
    }
    float acc = 0.f, z = 0.f;
#pragma unroll
    for (int t = 0; t < 16; ++t) {
        int r = 4 * yo - 6 + t;
        if (r < 0 || r >= FH) continue;
        float w = keysc(fabsf((float)t - 7.5f) * 0.25f);
        z += w;
        acc += w * src[r * FW + x];
    }
    RH[idx] = acc / z;
}

// ---------------- K5: unfold census patches (channel-last, padded to 84) ---
// U[img4][pos][84]: img4 = 2*j + b -> CD image 2+img4; f in [0,81) = [c][ky][kx]
__global__ void k_unfold(const float* __restrict__ CD, float* __restrict__ U) {
    int idx = blockIdx.x * 256 + threadIdx.x;
    const int total = 4 * PLANE * 84;
    if (idx >= total) return;
    int f   = idx % 84;
    int t   = idx / 84;
    int pos = t % PLANE;
    int img = t / PLANE;           // 0..3
    float v = 0.f;
    if (f < 81) {
        int y = pos / DW, x = pos % DW;
        int c = f / 9, r = f % 9, ky = r / 3, kx = r % 3;
        int ry = refl(y + ky - 1, DH), rx = refl(x + kx - 1, DW);
        v = CD[((2 + img) * 9 + c) * PLANE + ry * DW + rx];
    }
    U[idx] = v;
}

// ---------------- K6: patch matching + loss, one wave per pixel ------------
// CD: [NIMG][9][DH][DW]; RD: [NIMG][3][DH][DW]; U: [4][PLANE][84]
__global__ __launch_bounds__(256) void k_match(const float* __restrict__ CD,
                                               const float* __restrict__ RD,
                                               const float* __restrict__ U,
                                               float* __restrict__ partial) {
    int wid  = threadIdx.x >> 6;
    int lane = threadIdx.x & 63;
    int pid  = blockIdx.x * 4 + wid;       // 0..18431
    int b = pid / PLANE;
    int p = pid % PLANE;
    int y = p / DW, x = p % DW;

    const float* CDp = CD + b * 9 * PLANE;

    int ry0[3], rx0[3];
#pragma unroll
    for (int kk = 0; kk < 3; ++kk) {
        ry0[kk] = refl(y + kk - 1, DH);
        rx0[kk] = refl(x + kk - 1, DW);
    }

    // stage center census patch (84 floats, pad=0) into per-wave LDS
    __shared__ float pl[4][84];
    for (int f = lane; f < 84; f += 64) {
        float v = 0.f;
        if (f < 81) {
            int c = f / 9, r = f % 9, ky = r / 3, kx = r % 3;
            v = CDp[(c * DH + ry0[ky]) * DW + rx0[kx]];
        }
        pl[wid][f] = v;
    }
    __syncthreads();

    const float4* p4 = (const float4*)pl[wid];

    // each lane evaluates candidates n = lane and n = lane + 64
    float best = INFINITY;
    int bestn = 127;
#pragma unroll
    for (int t = 0; t < 2; ++t) {
        int n = lane + 64 * t;
        if (n < 98) {
            int j = n / 49, rr = n % 49;
            int dy = rr / 7 - 3, dx = rr % 7 - 3;
            int yy = refl(y + dy, DH), xx = refl(x + dx, DW);   // first reflect
            const float4* u4 =
                (const float4*)(U + (size_t)(((2 * j + b) * PLANE) + yy * DW + xx) * 84);
            float n2 = 0.f, dot = 0.f;
#pragma unroll
            for (int k = 0; k < 21; ++k) {
                float4 q = u4[k];
                float4 pp = p4[k];
                n2  += q.x * q.x + q.y * q.y + q.z * q.z + q.w * q.w;
                dot += pp.x * q.x + pp.y * q.y + pp.z * q.z + pp.w * q.w;
            }
            float dis = n2 - 2.f * dot;   // p2 dropped: constant per pixel
            if (dis < best || (dis == best && n < bestn)) { best = dis; bestn = n; }
        }
    }

    // wave-wide argmin with first-occurrence (smallest n) tie-break
#pragma unroll
    for (int off = 32; off > 0; off >>= 1) {
        float ob = __shfl_xor(best, off);
        int   on = __shfl_xor(bestn, off);
        if (ob < best || (ob == best && on < bestn)) { best = ob; bestn = on; }
    }

    // gather matched raw patch: lanes 0..26, one feature each
    float loss = 0.f;
    {
        int j = bestn / 49, rr = bestn % 49;
        int dy = rr / 7 - 3, dx = rr % 7 - 3;
        int yy = refl(y + dy, DH), xx = refl(x + dx, DW);
        if (lane < 27) {
            int c = lane / 9, ky = (lane / 3) % 3, kx = lane % 3;
            int ry = refl(yy + ky - 1, DH), rx = refl(xx + kx - 1, DW);
            const float* RDp = RD + b * 3 * PLANE;
            const float* RDn = RD + (2 + 2 * j + b) * 3 * PLANE;
            float a = RDp[(c * DH + ry0[ky]) * DW + rx0[kx]];
            float m = RDn[(c * DH + ry) * DW + rx];
            float d = a - m;
            loss = d * d;
        }
    }
#pragma unroll
    for (int off = 32; off > 0; off >>= 1) loss += __shfl_xor(loss, off);

    __shared__ float red[4];
    if (lane == 0) red[wid] = loss;
    __syncthreads();
    if (threadIdx.x == 0)
        partial[blockIdx.x] = red[0] + red[1] + red[2] + red[3];
}

// ---------------- K7: final reduction --------------------------------------
#define NPART 4608
__global__ void k_final(const float* __restrict__ partial, float* __restrict__ out) {
    __shared__ float red[256];
    float v = 0.f;
    for (int i = threadIdx.x; i < NPART; i += 256) v += partial[i];
    red[threadIdx.x] = v;
    __syncthreads();
#pragma unroll
    for (int s = 128; s > 0; s >>= 1) {
        if (threadIdx.x < s) red[threadIdx.x] += red[threadIdx.x + s];
        __syncthreads();
    }
    // mean over [b=2, hw=9216, 27] with the 0.5 factor
    if (threadIdx.x == 0) out[0] = red[0] * (0.5f / 497664.0f);
}

extern "C" void kernel_launch(void* const* d_in, const int* in_sizes, int n_in,
                              void* d_out, int out_size, void* d_ws, size_t ws_size,
                              hipStream_t stream) {
    const float* pred = (const float*)d_in[0];   // [2,3,384,384]
    const float* I    = (const float*)d_in[1];   // [2,2,3,384,384]
    float* out = (float*)d_out;
    float* ws  = (float*)d_ws;

    // workspace layout (floats):
    //   CD   [0, 497664)                       6*9*96*96
    //   RD   [497664, 663552)                  6*3*96*96
    //   part [663552, 668160)                  4608
    //   scratch S = 668160:
    //     gray [S, S+884736)                   6*384*384
    //     CH   [S+884736, S+2875392)           6*9*96*384
    //     RH   [S+2875392, S+3538944)          6*3*96*384
    //   U aliases scratch (written after CH/RH are dead): [S, S+3096576)
    float* CD   = ws;
    float* RD   = CD + 497664;
    float* part = RD + 165888;
    float* S    = part + 4608;
    float* gray = S;
    float* CH   = S + 884736;
    float* RH   = CH + 1990656;
    float* U    = S;                          // 4*9216*84 = 3096576 floats

    k_gray<<<(NIMG * FH * FW + 255) / 256, 256, 0, stream>>>(pred, I, gray);
    k_census_downH<<<(NIMG * 9 * DH * FW + 255) / 256, 256, 0, stream>>>(gray, CH);
    k_raw_downH<<<(NIMG * 3 * DH * FW + 255) / 256, 256, 0, stream>>>(pred, I, RH);
    // one combined W-downsample over CH|RH rows -> CD|RD
    k_downW<<<((NIMG * 12 * DH) * DW + 255) / 256, 256, 0, stream>>>(CH, CD, NIMG * 12 * DH);
    // unfold neighbor census patches into channel-last padded rows (kills gray/CH/RH)
    k_unfold<<<(4 * PLANE * 84 + 255) / 256, 256, 0, stream>>>(CD, U);
    k_match<<<NPART, 256, 0, stream>>>(CD, RD, U, part);
    k_final<<<1, 256, 0, stream>>>(part, out);
}